// Round 4
// baseline (586.241 us; speedup 1.0000x reference)
//
#include <hip/hip_runtime.h>
#include <cmath>

#define NTOK 32768   // 8*4096 tokens
#define EMB  2048
#define NEXP 64
#define TOPK 8
#define BT   64      // tokens per block (4 waves x 16 tokens)
#define KC   64      // K-chunk staged in LDS (f32)
#define NCH  (EMB / KC)

typedef __attribute__((ext_vector_type(4))) double d4;

__global__ __launch_bounds__(256) void router_mfma(
    const float* __restrict__ X,   // [NTOK][EMB]
    const float* __restrict__ W,   // [NEXP][EMB]
    const float* __restrict__ Bv,  // [NEXP]
    float* __restrict__ out)       // probs [NTOK][64] fp32, then indices [NTOK][8] as fp32
{
    // double-buffered f32 LDS tiles, column XOR-swizzled (float4 granularity)
    __shared__ float xs[2][BT * KC];    // 2 x 16 KB
    __shared__ float ws[2][NEXP * KC];  // 2 x 16 KB

    const int tid  = threadIdx.x;
    const int lane = tid & 63;
    const int wv   = tid >> 6;        // wave: tokens wv*16 .. wv*16+15
    const int t0   = blockIdx.x * BT;
    const int eL   = lane & 15;       // A: token row; B: expert col
    const int q    = lane >> 4;       // fragment k offset
    const int sw   = 4 * (eL & 7);    // read-side XOR swizzle

    // acc[c] = D tile for experts c*16..c*16+15; init with bias (col-constant)
    d4 acc[4];
    #pragma unroll
    for (int c = 0; c < 4; ++c) {
        const double b = (double)Bv[c * 16 + eL];
        acc[c] = (d4){b, b, b, b};
    }

    float4 rx[4], rw[4];   // staging registers (global -> reg -> LDS)

    auto load_chunk = [&](int ch) {
        const int kc0 = ch * KC;
        #pragma unroll
        for (int j = 0; j < 4; ++j) {
            const int flat = tid + j * 256;    // 0..1023
            const int r    = flat >> 4;        // row 0..63
            const int a    = flat & 15;        // float4 column
            rx[j] = *(const float4*)&X[(size_t)(t0 + r) * EMB + kc0 + 4 * a];
            rw[j] = *(const float4*)&W[(size_t)r * EMB + kc0 + 4 * a];
        }
    };
    auto store_chunk = [&](int buf) {
        #pragma unroll
        for (int j = 0; j < 4; ++j) {
            const int flat = tid + j * 256;
            const int r    = flat >> 4;
            const int a    = flat & 15;
            const int col  = a ^ (r & 7);      // float4-granular XOR swizzle
            *(float4*)&xs[buf][r * KC + 4 * col] = rx[j];
            *(float4*)&ws[buf][r * KC + 4 * col] = rw[j];
        }
    };

    load_chunk(0);
    store_chunk(0);
    __syncthreads();

    for (int ch = 0; ch < NCH; ++ch) {
        const int cur = ch & 1;
        if (ch + 1 < NCH) load_chunk(ch + 1);   // issue loads; vmcnt waited at store

        const float* xb = &xs[cur][(wv * 16 + eL) * KC];
        const float* wb = ws[cur];
        #pragma unroll
        for (int k4 = 0; k4 < KC; k4 += 4) {
            const int kk = (k4 + q) ^ sw;
            const double aF = (double)xb[kk];
            #pragma unroll
            for (int c = 0; c < 4; ++c) {
                const double bF = (double)wb[(c * 16 + eL) * KC + kk];
                acc[c] = __builtin_amdgcn_mfma_f64_16x16x4f64(aF, bF, acc[c], 0, 0, 0);
            }
        }

        if (ch + 1 < NCH) store_chunk((ch + 1) & 1);
        __syncthreads();
    }

    // ---- epilogue: top-8 + masked softmax, fully in registers/shfl ----
    // f64 MFMA D layout (CDNA dgemm, output-vector-width=1):
    //   token row = (lane>>4) + 4*reg, expert col = c*16 + (lane&15)
    float* probs = out;                        // [NTOK][64]
    float* idxo  = out + (size_t)NTOK * NEXP;  // [NTOK][8] index values as f32

    #pragma unroll
    for (int i = 0; i < 4; ++i) {
        const int T = t0 + wv * 16 + q + 4 * i;
        double v[4];
        #pragma unroll
        for (int c = 0; c < 4; ++c) v[c] = acc[c][i];

        unsigned sel = 0;
        double m0 = 0.0;
        float ssum = 0.0f;
        int myIdx = 0;
        #pragma unroll
        for (int it = 0; it < TOPK; ++it) {
            // local best among unselected candidates (c ascending => lowest index on tie)
            double bv = -1.0e300;
            int    be = 1 << 30;
            #pragma unroll
            for (int c = 0; c < 4; ++c)
                if (!((sel >> c) & 1) && v[c] > bv) { bv = v[c]; be = c * 16 + eL; }
            // 16-lane group argmax (xor 1,2,4,8 stays inside the group)
            double gv = bv; int ge = be;
            #pragma unroll
            for (int off = 1; off <= 8; off <<= 1) {
                const double ov = __shfl_xor(gv, off, 64);
                const int    oe = __shfl_xor(ge, off, 64);
                if (ov > gv || (ov == gv && oe < ge)) { gv = ov; ge = oe; }
            }
            if (it == 0) m0 = gv;
            ssum += __expf((float)(gv - m0));
            if ((ge & 15) == eL) sel |= 1u << (ge >> 4);  // owner lane marks candidate
            if (eL == it) myIdx = ge;                     // lane 'it' records rank-it index
        }
        const float inv = 1.0f / ssum;
        #pragma unroll
        for (int c = 0; c < 4; ++c) {
            const float p = ((sel >> c) & 1) ? __expf((float)(v[c] - m0)) * inv : 0.0f;
            probs[(size_t)T * NEXP + c * 16 + eL] = p;
        }
        if (eL < TOPK) idxo[(size_t)T * TOPK + eL] = (float)myIdx;
    }
}

extern "C" void kernel_launch(void* const* d_in, const int* in_sizes, int n_in,
                              void* d_out, int out_size, void* d_ws, size_t ws_size,
                              hipStream_t stream) {
    const float* X = (const float*)d_in[0];
    const float* W = (const float*)d_in[1];
    const float* B = (const float*)d_in[2];
    router_mfma<<<NTOK / BT, 256, 0, stream>>>(X, W, B, (float*)d_out);
}

// Round 5
// 462.919 us; speedup vs baseline: 1.2664x; 1.2664x over previous
//
#include <hip/hip_runtime.h>
#include <cmath>

#define NTOK 32768   // 8*4096 tokens
#define EMB  2048
#define NEXP 64
#define TOPK 8
#define BT   64      // tokens per block (4 waves x 16 tokens)
#define KC   64      // K-chunk staged in LDS (f32)
#define NCH  (EMB / KC)

typedef __attribute__((ext_vector_type(4))) double d4;

__device__ __forceinline__ void gld16(const float* g, float* lds) {
    __builtin_amdgcn_global_load_lds(
        (const __attribute__((address_space(1))) void*)g,
        (__attribute__((address_space(3))) void*)lds,
        16, 0, 0);
}

__global__ __launch_bounds__(256) void router_mfma(
    const float* __restrict__ X,   // [NTOK][EMB]
    const float* __restrict__ W,   // [NEXP][EMB]
    const float* __restrict__ Bv,  // [NEXP]
    float* __restrict__ out)       // probs [NTOK][64] fp32, then indices [NTOK][8] as fp32
{
    // double-buffered f32 LDS tiles.
    // Swizzle: LDS[row][4c+b] = G[row][4(c^(row&7))+b]  (applied on the GLOBAL
    // address side, since global_load_lds forces dest = base + lane*16)
    __shared__ float xs[2][BT * KC];    // 2 x 16 KB
    __shared__ float ws[2][NEXP * KC];  // 2 x 16 KB

    const int tid  = threadIdx.x;
    const int lane = tid & 63;
    const int wv   = tid >> 6;        // wave: tokens wv*16 .. wv*16+15
    const int t0   = blockIdx.x * BT;
    const int eL   = lane & 15;       // A: token row; B: expert col
    const int q    = lane >> 4;       // fragment k offset
    const int sw   = 4 * (eL & 7);    // read-side XOR swizzle

    // acc[c] = D tile for experts c*16..c*16+15; init with bias (col-constant)
    d4 acc[4];
    #pragma unroll
    for (int c = 0; c < 4; ++c) {
        const double b = (double)Bv[c * 16 + eL];
        acc[c] = (d4){b, b, b, b};
    }

    // Per chunk, wave wv issues 8 global_load_lds (4 for X, 4 for W).
    // Instruction i covers rows 4i..4i+3 (1024 B contiguous LDS).
    auto stage = [&](int ch, int buf) {
        const int kc0 = ch * KC;
        #pragma unroll
        for (int s = 0; s < 4; ++s) {
            const int i  = 4 * wv + s;
            const int r  = 4 * i + (lane >> 4);       // this lane's row
            const int ag = (lane & 15) ^ (r & 7);     // swizzled global col4
            gld16(&X[(size_t)(t0 + r) * EMB + kc0 + 4 * ag], &xs[buf][i * 256]);
            gld16(&W[(size_t)r * EMB + kc0 + 4 * ag], &ws[buf][i * 256]);
        }
    };

    stage(0, 0);
    __syncthreads();   // vmcnt(0) drain -> chunk 0 resident

    for (int ch = 0; ch < NCH; ++ch) {
        const int cur = ch & 1;
        if (ch + 1 < NCH) stage(ch + 1, cur ^ 1);   // DMA overlaps MFMA phase below

        const float* xb = &xs[cur][(wv * 16 + eL) * KC];
        const float* wb = ws[cur];
        #pragma unroll
        for (int k4 = 0; k4 < KC; k4 += 4) {
            const int kk = (k4 + q) ^ sw;
            const double aF = (double)xb[kk];
            #pragma unroll
            for (int c = 0; c < 4; ++c) {
                const double bF = (double)wb[(c * 16 + eL) * KC + kk];
                acc[c] = __builtin_amdgcn_mfma_f64_16x16x4f64(aF, bF, acc[c], 0, 0, 0);
            }
        }
        __syncthreads();   // drains vmcnt(0): next-chunk DMA had whole MFMA phase to land
    }

    // ---- epilogue: top-8 + masked softmax, fully in registers/shfl ----
    // f64 MFMA D layout (CDNA dgemm, output-vector-width=1):
    //   token row = (lane>>4) + 4*reg, expert col = c*16 + (lane&15)
    float* probs = out;                        // [NTOK][64]
    float* idxo  = out + (size_t)NTOK * NEXP;  // [NTOK][8] index values as f32

    #pragma unroll
    for (int i = 0; i < 4; ++i) {
        const int T = t0 + wv * 16 + q + 4 * i;
        double v[4];
        #pragma unroll
        for (int c = 0; c < 4; ++c) v[c] = acc[c][i];

        unsigned sel = 0;
        double m0 = 0.0;
        float ssum = 0.0f;
        int myIdx = 0;
        #pragma unroll
        for (int it = 0; it < TOPK; ++it) {
            // local best among unselected candidates (c ascending => lowest index on tie)
            double bv = -1.0e300;
            int    be = 1 << 30;
            #pragma unroll
            for (int c = 0; c < 4; ++c)
                if (!((sel >> c) & 1) && v[c] > bv) { bv = v[c]; be = c * 16 + eL; }
            // 16-lane group argmax (xor 1,2,4,8 stays inside the group)
            double gv = bv; int ge = be;
            #pragma unroll
            for (int off = 1; off <= 8; off <<= 1) {
                const double ov = __shfl_xor(gv, off, 64);
                const int    oe = __shfl_xor(ge, off, 64);
                if (ov > gv || (ov == gv && oe < ge)) { gv = ov; ge = oe; }
            }
            if (it == 0) m0 = gv;
            ssum += __expf((float)(gv - m0));
            if ((ge & 15) == eL) sel |= 1u << (ge >> 4);  // owner lane marks candidate
            if (eL == it) myIdx = ge;                     // lane 'it' records rank-it index
        }
        const float inv = 1.0f / ssum;
        #pragma unroll
        for (int c = 0; c < 4; ++c) {
            const float p = ((sel >> c) & 1) ? __expf((float)(v[c] - m0)) * inv : 0.0f;
            probs[(size_t)T * NEXP + c * 16 + eL] = p;
        }
        if (eL < TOPK) idxo[(size_t)T * TOPK + eL] = (float)myIdx;
    }
}

extern "C" void kernel_launch(void* const* d_in, const int* in_sizes, int n_in,
                              void* d_out, int out_size, void* d_ws, size_t ws_size,
                              hipStream_t stream) {
    const float* X = (const float*)d_in[0];
    const float* W = (const float*)d_in[1];
    const float* B = (const float*)d_in[2];
    router_mfma<<<NTOK / BT, 256, 0, stream>>>(X, W, B, (float*)d_out);
}

// Round 6
// 454.480 us; speedup vs baseline: 1.2899x; 1.0186x over previous
//
#include <hip/hip_runtime.h>
#include <cmath>

#define NTOK 32768   // 8*4096 tokens
#define EMB  2048
#define NEXP 64
#define TOPK 8
#define BT   64      // tokens per block
#define KC   32      // K-chunk per k-group stage
#define KGN  2       // k-groups (split-K)
#define KSPAN (EMB / KGN)
#define NCH  (KSPAN / KC)

typedef __attribute__((ext_vector_type(4))) double d4;

__device__ __forceinline__ void gld16(const float* g, float* lds) {
    __builtin_amdgcn_global_load_lds(
        (const __attribute__((address_space(1))) void*)g,
        (__attribute__((address_space(3))) void*)lds,
        16, 0, 0);
}

__global__ __launch_bounds__(512) void router_mfma(
    const float* __restrict__ X,   // [NTOK][EMB]
    const float* __restrict__ W,   // [NEXP][EMB]
    const float* __restrict__ Bv,  // [NEXP]
    float* __restrict__ out)       // probs [NTOK][64] fp32, then indices [NTOK][8] as fp32
{
    // Per-k-group double-buffered f32 tiles. Swizzle (float4-granular, XOR on
    // the GLOBAL col since global_load_lds forces dest = base + lane*16):
    //   LDS[row][4a+b] = G[row][4(a^(row&7))+b]
    __shared__ __align__(16) float xs[KGN][2][BT * KC];    // 4 x 8 KB
    __shared__ __align__(16) float ws[KGN][2][NEXP * KC];  // 4 x 8 KB

    const int tid  = threadIdx.x;
    const int lane = tid & 63;
    const int wv   = tid >> 6;        // 0..7
    const int tt   = wv & 3;          // token tile: tokens tt*16..tt*16+15
    const int kg   = wv >> 2;         // k-group
    const int t0   = blockIdx.x * BT;
    const int eL   = lane & 15;       // A: token row; B: expert col
    const int q    = lane >> 4;       // fragment k offset
    const int sw   = 4 * (eL & 7);    // read-side XOR swizzle

    // acc[c] = partial D tile for experts c*16..c*16+15. Bias only in kg 0.
    d4 acc[4];
    #pragma unroll
    for (int c = 0; c < 4; ++c) {
        const double b = (kg == 0) ? (double)Bv[c * 16 + eL] : 0.0;
        acc[c] = (d4){b, b, b, b};
    }

    // Stage one KC-chunk of this k-group's X and W tiles.
    // 8 X-instrs + 8 W-instrs per tile, 2+2 per wave; instr i covers rows 8i..8i+7.
    auto stage = [&](int ch, int buf) {
        const int kc0 = kg * KSPAN + ch * KC;
        #pragma unroll
        for (int s = 0; s < 2; ++s) {
            const int i  = 2 * tt + s;                 // 0..7
            const int r  = 8 * i + (lane >> 3);        // this lane's row
            const int ag = (lane & 7) ^ (lane >> 3);   // swizzled global col4 (r&7 == lane>>3)
            gld16(&X[(size_t)(t0 + r) * EMB + kc0 + 4 * ag], &xs[kg][buf][i * 256]);
            gld16(&W[(size_t)r * EMB + kc0 + 4 * ag], &ws[kg][buf][i * 256]);
        }
    };

    stage(0, 0);
    __syncthreads();   // vmcnt drain -> chunk 0 resident

    for (int ch = 0; ch < NCH; ++ch) {
        const int cur = ch & 1;
        if (ch + 1 < NCH) stage(ch + 1, cur ^ 1);   // DMA overlaps MFMA phase

        const float* xb = &xs[kg][cur][(tt * 16 + eL) * KC];
        const float* wb = ws[kg][cur];
        #pragma unroll
        for (int k4 = 0; k4 < KC; k4 += 4) {
            const int kk = (k4 + q) ^ sw;
            const double aF = (double)xb[kk];
            #pragma unroll
            for (int c = 0; c < 4; ++c) {
                const double bF = (double)wb[(c * 16 + eL) * KC + kk];
                acc[c] = __builtin_amdgcn_mfma_f64_16x16x4f64(aF, bF, acc[c], 0, 0, 0);
            }
        }
        __syncthreads();   // next-chunk DMA had the whole MFMA phase to land
    }

    // ---- combine split-K partials through LDS ----
    // part[(tt*16 + c*4 + i)*64 + lane]: 2-way-free bank pattern, 32 KB (reuses xs)
    double* part = (double*)xs;
    if (kg == 1) {
        #pragma unroll
        for (int c = 0; c < 4; ++c)
            #pragma unroll
            for (int i = 0; i < 4; ++i)
                part[(size_t)(tt * 16 + c * 4 + i) * 64 + lane] = acc[c][i];
    }
    __syncthreads();
    if (kg == 1) return;

    #pragma unroll
    for (int c = 0; c < 4; ++c)
        #pragma unroll
        for (int i = 0; i < 4; ++i)
            acc[c][i] += part[(size_t)(tt * 16 + c * 4 + i) * 64 + lane];

    // ---- epilogue: top-8 + masked softmax (kg 0 waves only) ----
    // f64 MFMA D layout: token row = (lane>>4) + 4*reg, expert col = c*16 + (lane&15)
    float* probs = out;                        // [NTOK][64]
    float* idxo  = out + (size_t)NTOK * NEXP;  // [NTOK][8] index values as f32

    #pragma unroll
    for (int i = 0; i < 4; ++i) {
        const int T = t0 + tt * 16 + q + 4 * i;
        double v[4];
        #pragma unroll
        for (int c = 0; c < 4; ++c) v[c] = acc[c][i];

        unsigned sel = 0;
        double m0 = 0.0;
        float ssum = 0.0f;
        int myIdx = 0;
        #pragma unroll
        for (int it = 0; it < TOPK; ++it) {
            // local best among unselected candidates (c ascending => lowest index on tie)
            double bv = -1.0e300;
            int    be = 1 << 30;
            #pragma unroll
            for (int c = 0; c < 4; ++c)
                if (!((sel >> c) & 1) && v[c] > bv) { bv = v[c]; be = c * 16 + eL; }
            // 16-lane group argmax (xor 1,2,4,8 stays inside the group)
            double gv = bv; int ge = be;
            #pragma unroll
            for (int off = 1; off <= 8; off <<= 1) {
                const double ov = __shfl_xor(gv, off, 64);
                const int    oe = __shfl_xor(ge, off, 64);
                if (ov > gv || (ov == gv && oe < ge)) { gv = ov; ge = oe; }
            }
            if (it == 0) m0 = gv;
            ssum += __expf((float)(gv - m0));
            if ((ge & 15) == eL) sel |= 1u << (ge >> 4);  // owner lane marks candidate
            if (eL == it) myIdx = ge;                     // lane 'it' records rank-it index
        }
        const float inv = 1.0f / ssum;
        #pragma unroll
        for (int c = 0; c < 4; ++c) {
            const float p = ((sel >> c) & 1) ? __expf((float)(v[c] - m0)) * inv : 0.0f;
            probs[(size_t)T * NEXP + c * 16 + eL] = p;
        }
        if (eL < TOPK) idxo[(size_t)T * TOPK + eL] = (float)myIdx;
    }
}

extern "C" void kernel_launch(void* const* d_in, const int* in_sizes, int n_in,
                              void* d_out, int out_size, void* d_ws, size_t ws_size,
                              hipStream_t stream) {
    const float* X = (const float*)d_in[0];
    const float* W = (const float*)d_in[1];
    const float* B = (const float*)d_in[2];
    router_mfma<<<NTOK / BT, 512, 0, stream>>>(X, W, B, (float*)d_out);
}